// Round 17
// baseline (196.977 us; speedup 1.0000x reference)
//
#include <hip/hip_runtime.h>

// Problem constants (fixed by the reference)
#define NXY   16
#define NZ    8
#define NS    2048      // states = 16*16*8
#define NT    2048      // tokens
#define NB    16        // stories
#define NL    16        // story length
#define NSENT 16        // tokens per sentence
#define NEGV  (-1e9f)

#define NBLK  1024      // 4 blocks/CU x 256 CUs -- exactly co-resident
#define TT    16
#define SPAD  17
#define FPF   16        // forward buffer front guard pad
#define FPB   512       // forward buffer back guard pad
#define FTOT  (FPF + NS + FPB)   // 2576

// LDS union: smooth tile / eall toks / forward ping-pong (phases disjoint)
struct __align__(16) ShU {
    union {
        float S[256 * SPAD];                 // 17408 B (phase A)
        int   toks[NSENT];                   // 64 B    (phase B)
        struct { float A[FTOT]; float B[FTOT]; } f;   // 20608 B (phase C)
    };
};

// R5-proven grid barrier halves (counters zeroed by captured hipMemsetAsync).
__device__ __forceinline__ void gsignal(unsigned* ctr) {
    __syncthreads();                          // all lanes' writes retired
    if (threadIdx.x == 0) { __threadfence(); atomicAdd(ctr, 1u); }
}
__device__ __forceinline__ void gwait(unsigned* ctr) {
    if (threadIdx.x == 0) {
        while (__hip_atomic_load(ctr, __ATOMIC_RELAXED, __HIP_MEMORY_SCOPE_AGENT)
               < (unsigned)NBLK)
            __builtin_amdgcn_s_sleep(8);
        __threadfence();                      // acquire
    }
    __syncthreads();
}

__global__ __launch_bounds__(256, 4) void k_fused(
        const int* __restrict__ stories, const float* __restrict__ priors,
        const float* __restrict__ trans, const float* __restrict__ em,
        float* __restrict__ emT, float* __restrict__ eall,
        float* __restrict__ wtab, unsigned* __restrict__ ctrs,
        float* __restrict__ out) {
    __shared__ ShU sh;
    const int tid = threadIdx.x;
    const int blk = blockIdx.x;

    // ---- Phase A: smooth tile (round-6 proven body) + 14 wtab prep elems ----
    {
        // prep: g in [0, 7*NS); 1024 blocks x 14 = 14336 exactly
        if (tid < 14) {
            const int g = blk * 14 + tid;
            const int k = g >> 11;
            const int h = g & (NS - 1);
            const int x = h & 15, y = (h >> 4) & 15, z = h >> 8;
            const float* row = trans + (size_t)h * NS;
            float w;
            switch (k) {
                case 0: w = row[h]; break;
                case 1: w = (x < 15) ? row[h + 1]   : NEGV; break;
                case 2: w = (x > 0)  ? row[h - 1]   : NEGV; break;
                case 3: w = (y < 15) ? row[h + 16]  : NEGV; break;
                case 4: w = (y > 0)  ? row[h - 16]  : NEGV; break;
                case 5: w = (z < 7)  ? row[h + 256] : NEGV; break;
                default: w = (z < 6) ? row[h + 512] : NEGV; break;
            }
            wtab[g] = w;
        }

        const int t0 = (blk & 127) * TT;
        const int z = blk >> 7;
        const int toff = tid & 15, y = tid >> 4;

        const float* base = em + ((size_t)z * 256 + y * 16) * NT + t0 + toff;
        float ex[16];
#pragma unroll
        for (int x = 0; x < 16; ++x)
            ex[x] = __expf(base[(size_t)x * NT]);

#pragma unroll
        for (int x = 0; x < 16; ++x) {
            const int xm2 = x - 2 < 0 ? 0 : x - 2, xm1 = x - 1 < 0 ? 0 : x - 1;
            const int xp1 = x + 1 > 15 ? 15 : x + 1, xp2 = x + 2 > 15 ? 15 : x + 2;
            sh.S[(y * 16 + x) * SPAD + toff] =
                ex[xm2] + ex[xm1] + ex[x] + ex[xp1] + ex[xp2];
        }
        __syncthreads();

        const int x2 = tid & 15, y2 = tid >> 4;
        int ry[5];
#pragma unroll
        for (int k = 0; k < 5; ++k) {
            int yy = y2 + k - 2; yy = yy < 0 ? 0 : (yy > 15 ? 15 : yy);
            ry[k] = (yy * 16 + x2) * SPAD;
        }
        const float LOG25 = 3.2188758248682006f;
        float* ob = emT + (size_t)t0 * NS + z * 256 + tid;
#pragma unroll
        for (int t = 0; t < TT; ++t) {
            float a = sh.S[ry[0] + t] + sh.S[ry[1] + t] + sh.S[ry[2] + t] +
                      sh.S[ry[3] + t] + sh.S[ry[4] + t];
            ob[(size_t)t * NS] = __logf(a) - LOG25;
        }
    }

    gsignal(&ctrs[0]);

    if (blk >= 512) {             // no phase B/C work: signal both, leave
        gsignal(&ctrs[1]);
        return;
    }

    gwait(&ctrs[0]);

    // ---- Phase B: one eall item (bl, half) per block (round-2 proven) ----
    {
        const int bl = blk >> 1, half = blk & 1;
        const int col = half * 256 + tid;                  // float4 index
        if (tid < NSENT) sh.toks[tid] = stories[bl * NSENT + tid];
        __syncthreads();

        float4 a = make_float4(0.f, 0.f, 0.f, 0.f);
#pragma unroll 4
        for (int j = 0; j < NSENT; ++j) {
            float4 v = ((const float4*)(emT + (size_t)sh.toks[j] * NS))[col];
            a.x += v.x; a.y += v.y; a.z += v.z; a.w += v.w;
        }
        ((float4*)(eall + (size_t)bl * NS))[col] = a;
    }

    gsignal(&ctrs[1]);
    if (blk >= NB) return;
    gwait(&ctrs[1]);

    // ---- Phase C: forward, block = story, 256 threads x 4 even/odd pairs
    // (round-8 proven pair body; guard pads; wtab float2 weights) ----
    const int b = blk;
    float* A = sh.f.A + FPF;
    float* Bv = sh.f.B + FPF;

    for (int i = tid; i < FPF + FPB; i += 256) {     // zero guard pads
        int idx = (i < FPF) ? i : FPF + NS + (i - FPF);
        sh.f.A[idx] = 0.f;
        sh.f.B[idx] = 0.f;
    }

    float2 w[4][7];
#pragma unroll
    for (int q = 0; q < 4; ++q) {
        const int h0 = tid * 2 + q * 512;
#pragma unroll
        for (int k = 0; k < 7; ++k)
            w[q][k] = *(const float2*)(wtab + (size_t)k * NS + h0);
    }

    const float* eb = eall + (size_t)b * NL * NS;
    float2 vres[4];
#pragma unroll
    for (int q = 0; q < 4; ++q) {
        const int h0 = tid * 2 + q * 512;
        float2 e0 = *(const float2*)(eb + h0);
        float2 pr = *(const float2*)(priors + h0);
        vres[q] = make_float2(e0.x + pr.x, e0.y + pr.y);
        *(float2*)(A + h0) = vres[q];
        *(float2*)(out + (size_t)b * NS + h0) = vres[q];
    }
    __syncthreads();

    float* prev = A;
    float* cur = Bv;
    for (int l = 1; l < NL; ++l) {
#pragma unroll
        for (int q = 0; q < 4; ++q) {
            const int h0 = tid * 2 + q * 512;
            float2 c0 = *(const float2*)(prev + h0);
            float  xl = prev[h0 - 1];
            float  xr = prev[h0 + 2];
            float2 ym = *(const float2*)(prev + h0 - 16);
            float2 yp = *(const float2*)(prev + h0 + 16);
            float2 z1 = *(const float2*)(prev + h0 + 256);
            float2 z2 = *(const float2*)(prev + h0 + 512);
            float2 ec = *(const float2*)(eb + (size_t)l * NS + h0);

            float a0 = w[q][0].x + c0.x, a1 = w[q][1].x + c0.y, a2 = w[q][2].x + xl;
            float a3 = w[q][3].x + yp.x, a4 = w[q][4].x + ym.x;
            float a5 = w[q][5].x + z1.x, a6 = w[q][6].x + z2.x;
            float m0 = fmaxf(fmaxf(fmaxf(a0, a1), fmaxf(a2, a3)),
                             fmaxf(fmaxf(a4, a5), a6));
            float s0 = __expf(a0 - m0) + __expf(a1 - m0) + __expf(a2 - m0) +
                       __expf(a3 - m0) + __expf(a4 - m0) + __expf(a5 - m0) +
                       __expf(a6 - m0);

            float b0 = w[q][0].y + c0.y, b1 = w[q][1].y + xr, b2 = w[q][2].y + c0.x;
            float b3 = w[q][3].y + yp.y, b4 = w[q][4].y + ym.y;
            float b5 = w[q][5].y + z1.y, b6 = w[q][6].y + z2.y;
            float m1 = fmaxf(fmaxf(fmaxf(b0, b1), fmaxf(b2, b3)),
                             fmaxf(fmaxf(b4, b5), b6));
            float s1 = __expf(b0 - m1) + __expf(b1 - m1) + __expf(b2 - m1) +
                       __expf(b3 - m1) + __expf(b4 - m1) + __expf(b5 - m1) +
                       __expf(b6 - m1);

            vres[q] = make_float2(ec.x + m0 + __logf(s0), ec.y + m1 + __logf(s1));
            *(float2*)(cur + h0) = vres[q];
            *(float2*)(out + ((size_t)l * NB + b) * NS + h0) = vres[q];
        }
        __syncthreads();
        float* tmp = prev; prev = cur; cur = tmp;
    }
}

// ---------------------------------------------------------------------------
extern "C" void kernel_launch(void* const* d_in, const int* in_sizes, int n_in,
                              void* d_out, int out_size, void* d_ws, size_t ws_size,
                              hipStream_t stream) {
    (void)in_sizes; (void)n_in; (void)out_size; (void)ws_size;
    const int* stories  = (const int*)d_in[0];
    // d_in[1] = story_length (== NL), unused
    const float* priors = (const float*)d_in[2];
    const float* trans  = (const float*)d_in[3];
    const float* em     = (const float*)d_in[4];
    float* out = (float*)d_out;

    float* emT  = (float*)d_ws;                              // [NT][NS]    16 MB
    float* eall = emT + (size_t)NT * NS;                     // [NB*NL][NS]  2 MB
    float* wtab = eall + (size_t)NB * NL * NS;               // [7][NS]     57 KB
    unsigned* ctrs = (unsigned*)((char*)d_ws + (33u << 20)); // isolated line

    hipMemsetAsync(ctrs, 0, 2 * sizeof(unsigned), stream);   // capture-safe
    k_fused<<<dim3(NBLK), 256, 0, stream>>>(stories, priors, trans, em,
                                            emT, eall, wtab, ctrs, out);
}

// Round 18
// 110.073 us; speedup vs baseline: 1.7895x; 1.7895x over previous
//
#include <hip/hip_runtime.h>

// Problem constants (fixed by the reference)
#define NXY   16
#define NZ    8
#define NS    2048      // states = 16*16*8
#define NT    2048      // tokens
#define NB    16        // stories
#define NL    16        // story length
#define NSENT 16        // tokens per sentence
#define NEGV  (-1e9f)

#define NBLK  1024      // 4 blocks/CU x 256 CUs -- exactly co-resident
#define TT    16
#define SPAD  17
#define FPF   16        // forward buffer front guard pad
#define FPB   512       // forward buffer back guard pad
#define FTOT  (FPF + NS + FPB)   // 2576

// Counter lines, 64B apart (16 u32 stride) to avoid line contention.
// ctrT[128]: token-tile readiness (quota 8 = z-blocks per tile)
// ctrW[16] : phase-A complete, for wtab   (quota 64 per line, 1024 total)
// ctrS[16] : per-story eall readiness     (quota 32)
#define CTR_TILE(i)  ((i) * 16)
#define CTR_WTAB(i)  (2048 + (i) * 16)
#define CTR_STORY(i) (2304 + (i) * 16)
#define CTR_TOTAL    2560                 // u32s -> 10240 B memset

// LDS union: smooth tile / eall toks / forward ping-pong (phases disjoint)
struct __align__(16) ShU {
    union {
        float S[256 * SPAD];                          // 17408 B (phase A)
        int   toks[NSENT];                            // 64 B    (phase B)
        struct { float A[FTOT]; float B[FTOT]; } f;   // 20608 B (phase C)
    };
};

__global__ __launch_bounds__(256, 4) void k_fused(
        const int* __restrict__ stories, const float* __restrict__ priors,
        const float* __restrict__ trans, const float* __restrict__ em,
        float* __restrict__ emT, float* __restrict__ eall,
        float* __restrict__ wtab, unsigned* __restrict__ ctrs,
        float* __restrict__ out) {
    __shared__ ShU sh;
    const int tid = threadIdx.x;
    const int blk = blockIdx.x;

    // ---- Phase A: smooth tile (R17-validated body) + 14 wtab prep elems ----
    {
        if (tid < 14) {
            const int g = blk * 14 + tid;              // covers [0, 7*NS) exactly
            const int k = g >> 11;
            const int h = g & (NS - 1);
            const int x = h & 15, y = (h >> 4) & 15, z = h >> 8;
            const float* row = trans + (size_t)h * NS;
            float w;
            switch (k) {
                case 0: w = row[h]; break;
                case 1: w = (x < 15) ? row[h + 1]   : NEGV; break;
                case 2: w = (x > 0)  ? row[h - 1]   : NEGV; break;
                case 3: w = (y < 15) ? row[h + 16]  : NEGV; break;
                case 4: w = (y > 0)  ? row[h - 16]  : NEGV; break;
                case 5: w = (z < 7)  ? row[h + 256] : NEGV; break;
                default: w = (z < 6) ? row[h + 512] : NEGV; break;
            }
            wtab[g] = w;
        }

        const int t0 = (blk & 127) * TT;
        const int z = blk >> 7;
        const int toff = tid & 15, y = tid >> 4;

        const float* base = em + ((size_t)z * 256 + y * 16) * NT + t0 + toff;
        float ex[16];
#pragma unroll
        for (int x = 0; x < 16; ++x)
            ex[x] = __expf(base[(size_t)x * NT]);

#pragma unroll
        for (int x = 0; x < 16; ++x) {
            const int xm2 = x - 2 < 0 ? 0 : x - 2, xm1 = x - 1 < 0 ? 0 : x - 1;
            const int xp1 = x + 1 > 15 ? 15 : x + 1, xp2 = x + 2 > 15 ? 15 : x + 2;
            sh.S[(y * 16 + x) * SPAD + toff] =
                ex[xm2] + ex[xm1] + ex[x] + ex[xp1] + ex[xp2];
        }
        __syncthreads();

        const int x2 = tid & 15, y2 = tid >> 4;
        int ry[5];
#pragma unroll
        for (int k = 0; k < 5; ++k) {
            int yy = y2 + k - 2; yy = yy < 0 ? 0 : (yy > 15 ? 15 : yy);
            ry[k] = (yy * 16 + x2) * SPAD;
        }
        const float LOG25 = 3.2188758248682006f;
        float* ob = emT + (size_t)t0 * NS + z * 256 + tid;
#pragma unroll
        for (int t = 0; t < TT; ++t) {
            float a = sh.S[ry[0] + t] + sh.S[ry[1] + t] + sh.S[ry[2] + t] +
                      sh.S[ry[3] + t] + sh.S[ry[4] + t];
            ob[(size_t)t * NS] = __logf(a) - LOG25;
        }
    }

    // signal: my token-tile line + phase-A-global line (writes fenced first)
    __syncthreads();
    if (tid == 0) {
        __threadfence();
        atomicAdd(&ctrs[CTR_TILE(blk & 127)], 1u);
        atomicAdd(&ctrs[CTR_WTAB(blk & 15)], 1u);
    }

    if (blk >= 512) return;                    // no phase B/C work

    // ---- Phase B: wait ONLY for my 16 tokens' tiles, then eall item --------
    const int bl = blk >> 1, half = blk & 1;
    if (tid < NSENT) sh.toks[tid] = stories[bl * NSENT + tid];
    __syncthreads();

    if (tid < 16) {
        const int line = CTR_TILE(sh.toks[tid] >> 4);
        bool done = false;
        while (!done) {
            // RMW poll: always served at the coherence point (the R5/R17
            // stale-L2 plain-load poll cost ~140us of blind spinning)
            unsigned v = atomicAdd(&ctrs[line], 0u);
            done = ((__ballot(v >= 8u) & 0xFFFFull) == 0xFFFFull);
            if (!done) __builtin_amdgcn_s_sleep(32);
        }
        if (tid == 0) __threadfence();         // acquire
    }
    __syncthreads();

    {
        const int col = half * 256 + tid;                  // float4 index
        float4 a = make_float4(0.f, 0.f, 0.f, 0.f);
#pragma unroll 4
        for (int j = 0; j < NSENT; ++j) {
            float4 v = ((const float4*)(emT + (size_t)sh.toks[j] * NS))[col];
            a.x += v.x; a.y += v.y; a.z += v.z; a.w += v.w;
        }
        ((float4*)(eall + (size_t)bl * NS))[col] = a;
    }

    __syncthreads();
    if (tid == 0) {
        __threadfence();
        atomicAdd(&ctrs[CTR_STORY(blk >> 5)], 1u);   // story = bl>>4 = blk>>5
    }

    if (blk >= NB) return;

    // ---- Phase C waits: all phase-A (wtab) + my story's 32 eall blocks ----
    if (tid < 16) {
        const int line = CTR_WTAB(tid);
        bool done = false;
        while (!done) {
            unsigned v = atomicAdd(&ctrs[line], 0u);
            done = ((__ballot(v >= 64u) & 0xFFFFull) == 0xFFFFull);
            if (!done) __builtin_amdgcn_s_sleep(32);
        }
    }
    if (tid == 0) {
        while (atomicAdd(&ctrs[CTR_STORY(blk)], 0u) < 32u)
            __builtin_amdgcn_s_sleep(16);
        __threadfence();                       // acquire
    }
    __syncthreads();

    // ---- Phase C: forward (R17-validated body): 256 thr x 4 even/odd pairs
    const int b = blk;
    float* A = sh.f.A + FPF;
    float* Bv = sh.f.B + FPF;

    for (int i = tid; i < FPF + FPB; i += 256) {     // zero guard pads
        int idx = (i < FPF) ? i : FPF + NS + (i - FPF);
        sh.f.A[idx] = 0.f;
        sh.f.B[idx] = 0.f;
    }

    float2 w[4][7];
#pragma unroll
    for (int q = 0; q < 4; ++q) {
        const int h0 = tid * 2 + q * 512;
#pragma unroll
        for (int k = 0; k < 7; ++k)
            w[q][k] = *(const float2*)(wtab + (size_t)k * NS + h0);
    }

    const float* eb = eall + (size_t)b * NL * NS;
    float2 vres[4];
#pragma unroll
    for (int q = 0; q < 4; ++q) {
        const int h0 = tid * 2 + q * 512;
        float2 e0 = *(const float2*)(eb + h0);
        float2 pr = *(const float2*)(priors + h0);
        vres[q] = make_float2(e0.x + pr.x, e0.y + pr.y);
        *(float2*)(A + h0) = vres[q];
        *(float2*)(out + (size_t)b * NS + h0) = vres[q];
    }
    __syncthreads();

    float* prev = A;
    float* cur = Bv;
    for (int l = 1; l < NL; ++l) {
#pragma unroll
        for (int q = 0; q < 4; ++q) {
            const int h0 = tid * 2 + q * 512;
            float2 c0 = *(const float2*)(prev + h0);
            float  xl = prev[h0 - 1];
            float  xr = prev[h0 + 2];
            float2 ym = *(const float2*)(prev + h0 - 16);
            float2 yp = *(const float2*)(prev + h0 + 16);
            float2 z1 = *(const float2*)(prev + h0 + 256);
            float2 z2 = *(const float2*)(prev + h0 + 512);
            float2 ec = *(const float2*)(eb + (size_t)l * NS + h0);

            float a0 = w[q][0].x + c0.x, a1 = w[q][1].x + c0.y, a2 = w[q][2].x + xl;
            float a3 = w[q][3].x + yp.x, a4 = w[q][4].x + ym.x;
            float a5 = w[q][5].x + z1.x, a6 = w[q][6].x + z2.x;
            float m0 = fmaxf(fmaxf(fmaxf(a0, a1), fmaxf(a2, a3)),
                             fmaxf(fmaxf(a4, a5), a6));
            float s0 = __expf(a0 - m0) + __expf(a1 - m0) + __expf(a2 - m0) +
                       __expf(a3 - m0) + __expf(a4 - m0) + __expf(a5 - m0) +
                       __expf(a6 - m0);

            float b0 = w[q][0].y + c0.y, b1 = w[q][1].y + xr, b2 = w[q][2].y + c0.x;
            float b3 = w[q][3].y + yp.y, b4 = w[q][4].y + ym.y;
            float b5 = w[q][5].y + z1.y, b6 = w[q][6].y + z2.y;
            float m1 = fmaxf(fmaxf(fmaxf(b0, b1), fmaxf(b2, b3)),
                             fmaxf(fmaxf(b4, b5), b6));
            float s1 = __expf(b0 - m1) + __expf(b1 - m1) + __expf(b2 - m1) +
                       __expf(b3 - m1) + __expf(b4 - m1) + __expf(b5 - m1) +
                       __expf(b6 - m1);

            vres[q] = make_float2(ec.x + m0 + __logf(s0), ec.y + m1 + __logf(s1));
            *(float2*)(cur + h0) = vres[q];
            *(float2*)(out + ((size_t)l * NB + b) * NS + h0) = vres[q];
        }
        __syncthreads();
        float* tmp = prev; prev = cur; cur = tmp;
    }
}

// ---------------------------------------------------------------------------
extern "C" void kernel_launch(void* const* d_in, const int* in_sizes, int n_in,
                              void* d_out, int out_size, void* d_ws, size_t ws_size,
                              hipStream_t stream) {
    (void)in_sizes; (void)n_in; (void)out_size; (void)ws_size;
    const int* stories  = (const int*)d_in[0];
    // d_in[1] = story_length (== NL), unused
    const float* priors = (const float*)d_in[2];
    const float* trans  = (const float*)d_in[3];
    const float* em     = (const float*)d_in[4];
    float* out = (float*)d_out;

    float* emT  = (float*)d_ws;                              // [NT][NS]    16 MB
    float* eall = emT + (size_t)NT * NS;                     // [NB*NL][NS]  2 MB
    float* wtab = eall + (size_t)NB * NL * NS;               // [7][NS]     57 KB
    unsigned* ctrs = (unsigned*)((char*)d_ws + (33u << 20)); // isolated region

    hipMemsetAsync(ctrs, 0, CTR_TOTAL * sizeof(unsigned), stream);
    k_fused<<<dim3(NBLK), 256, 0, stream>>>(stories, priors, trans, em,
                                            emT, eall, wtab, ctrs, out);
}

// Round 20
// 37.863 us; speedup vs baseline: 5.2024x; 2.9072x over previous
//
#include <hip/hip_runtime.h>

// Problem constants (fixed by the reference)
#define NXY   16
#define NZ    8
#define NS    2048      // states = 16*16*8
#define NT    2048      // tokens
#define NB    16        // stories
#define NL    16        // story length
#define NSENT 16        // tokens per sentence
#define NEGV  (-1e9f)

// ---------------------------------------------------------------------------
// K1 v3: fused smoothing + transpose (round-6 proven body) PLUS the wtab
// prep (round-10 proven body) as extra grid blocks (blockIdx.y == 8).
// (round-12/13 proven, unchanged)
// ---------------------------------------------------------------------------
#define TT   16
#define SPAD 17

__global__ __launch_bounds__(256) void k_smooth(const float* __restrict__ em,
                                                float* __restrict__ emT,
                                                const float* __restrict__ trans,
                                                float* __restrict__ wtab) {
    const int tid = threadIdx.x;

    if (blockIdx.y == NZ) {
        // ---- prep path: one thread per (neighbor-slot, state)
        const int g = blockIdx.x * 256 + tid;          // [0, 32768)
        if (g < 7 * NS) {
            const int k = g >> 11;
            const int h = g & (NS - 1);
            const int x = h & 15, y = (h >> 4) & 15, z = h >> 8;
            const float* row = trans + (size_t)h * NS;
            float w;
            switch (k) {
                case 0: w = row[h]; break;
                case 1: w = (x < 15) ? row[h + 1]   : NEGV; break;
                case 2: w = (x > 0)  ? row[h - 1]   : NEGV; break;
                case 3: w = (y < 15) ? row[h + 16]  : NEGV; break;
                case 4: w = (y > 0)  ? row[h - 16]  : NEGV; break;
                case 5: w = (z < 7)  ? row[h + 256] : NEGV; break;
                default: w = (z < 6) ? row[h + 512] : NEGV; break;
            }
            wtab[g] = w;
        }
        return;
    }

    // ---- smooth path (round-6 body, unchanged)
    __shared__ float S[256 * SPAD];   // 17408 B
    const int t0 = blockIdx.x * TT;
    const int z = blockIdx.y;
    const int toff = tid & 15, y = tid >> 4;

    const float* base = em + ((size_t)z * 256 + y * 16) * NT + t0 + toff;
    float ex[16];
#pragma unroll
    for (int x = 0; x < 16; ++x)
        ex[x] = __expf(base[(size_t)x * NT]);

#pragma unroll
    for (int x = 0; x < 16; ++x) {
        const int xm2 = x - 2 < 0 ? 0 : x - 2, xm1 = x - 1 < 0 ? 0 : x - 1;
        const int xp1 = x + 1 > 15 ? 15 : x + 1, xp2 = x + 2 > 15 ? 15 : x + 2;
        S[(y * 16 + x) * SPAD + toff] = ex[xm2] + ex[xm1] + ex[x] + ex[xp1] + ex[xp2];
    }
    __syncthreads();

    const int x2 = tid & 15, y2 = tid >> 4;
    int ry[5];
#pragma unroll
    for (int k = 0; k < 5; ++k) {
        int yy = y2 + k - 2; yy = yy < 0 ? 0 : (yy > 15 ? 15 : yy);
        ry[k] = (yy * 16 + x2) * SPAD;
    }
    const float LOG25 = 3.2188758248682006f;   // log(5)+log(5)
    float* ob = emT + (size_t)t0 * NS + z * 256 + tid;
#pragma unroll
    for (int t = 0; t < TT; ++t) {
        float a = S[ry[0] + t] + S[ry[1] + t] + S[ry[2] + t] + S[ry[3] + t] + S[ry[4] + t];
        ob[(size_t)t * NS] = __logf(a) - LOG25;
    }
}

// ---------------------------------------------------------------------------
// K2: e_all[b,l,s] = sum_j em_T[tok[b,l,j], s]   (round-2 proven, unchanged)
// ---------------------------------------------------------------------------
__global__ __launch_bounds__(256) void k_eall(const int* __restrict__ stories,
                                              const float* __restrict__ emT,
                                              float* __restrict__ eall) {
    const int bl = blockIdx.x;
    const int col = blockIdx.y * 256 + threadIdx.x;
    __shared__ int toks[NSENT];
    if (threadIdx.x < NSENT) toks[threadIdx.x] = stories[bl * NSENT + threadIdx.x];
    __syncthreads();

    float4 a = make_float4(0.f, 0.f, 0.f, 0.f);
#pragma unroll 4
    for (int j = 0; j < NSENT; ++j) {
        float4 v = ((const float4*)(emT + (size_t)toks[j] * NS))[col];
        a.x += v.x; a.y += v.y; a.z += v.z; a.w += v.w;
    }
    ((float4*)(eall + (size_t)bl * NS))[col] = a;
}

// ---------------------------------------------------------------------------
// K3 v8 (round-13 proven, 37.0us total): round-2 forward body + all 15 e-rows
// staged into LDS in the prologue; weights from the compact wtab.
// Dynamic LDS: 15*NS + 2*NS floats = 139264 B.
// ---------------------------------------------------------------------------
__global__ __launch_bounds__(1024) void k_forward(const float* __restrict__ wtab,
                                                  const float* __restrict__ priors,
                                                  const float* __restrict__ eall,
                                                  float* __restrict__ out) {
    extern __shared__ float smem[];
    float* ebuf = smem;                    // [NL-1][NS]  (rows l=1..15)
    float* buf0 = smem + (NL - 1) * NS;    // [NS]
    float* buf1 = buf0 + NS;               // [NS]

    const int b = blockIdx.x;
    const int tid = threadIdx.x;
    const float* eb = eall + (size_t)b * NL * NS;

    // stage e rows 1..15 into LDS (fully coalesced float2, deep MLP)
    {
        const float2* src = (const float2*)(eb + NS);
        float2* dst = (float2*)ebuf;
#pragma unroll
        for (int i = 0; i < (NL - 1) * NS / 2048; ++i)     // 15 iters
            dst[i * 1024 + tid] = src[i * 1024 + tid];
    }

    float wr[2][7];
    int   ix[2][7];
#pragma unroll
    for (int p = 0; p < 2; ++p) {
        const int h = tid + p * 1024;
        const int x = h & 15, y = (h >> 4) & 15, z = h >> 8;
        wr[p][0] = wtab[0 * NS + h];  ix[p][0] = h;
        wr[p][1] = wtab[1 * NS + h];  ix[p][1] = (x < 15) ? h + 1   : h;
        wr[p][2] = wtab[2 * NS + h];  ix[p][2] = (x > 0)  ? h - 1   : h;
        wr[p][3] = wtab[3 * NS + h];  ix[p][3] = (y < 15) ? h + 16  : h;
        wr[p][4] = wtab[4 * NS + h];  ix[p][4] = (y > 0)  ? h - 16  : h;
        wr[p][5] = wtab[5 * NS + h];  ix[p][5] = (z < 7)  ? h + 256 : h;
        wr[p][6] = wtab[6 * NS + h];  ix[p][6] = (z < 6)  ? h + 512 : h;
        float v = eb[h] + priors[h];
        buf0[h] = v;
        out[(size_t)b * NS + h] = v;
    }
    __syncthreads();

    float* prev = buf0;
    float* cur = buf1;
    for (int l = 1; l < NL; ++l) {
        const float* e = ebuf + (size_t)(l - 1) * NS;     // LDS, not global
#pragma unroll
        for (int p = 0; p < 2; ++p) {
            const int h = tid + p * 1024;
            float v0 = wr[p][0] + prev[ix[p][0]];
            float v1 = wr[p][1] + prev[ix[p][1]];
            float v2 = wr[p][2] + prev[ix[p][2]];
            float v3 = wr[p][3] + prev[ix[p][3]];
            float v4 = wr[p][4] + prev[ix[p][4]];
            float v5 = wr[p][5] + prev[ix[p][5]];
            float v6 = wr[p][6] + prev[ix[p][6]];
            float m = fmaxf(fmaxf(fmaxf(v0, v1), fmaxf(v2, v3)),
                            fmaxf(fmaxf(v4, v5), v6));
            float s = __expf(v0 - m) + __expf(v1 - m) + __expf(v2 - m) + __expf(v3 - m) +
                      __expf(v4 - m) + __expf(v5 - m) + __expf(v6 - m);
            float v = e[h] + m + __logf(s);
            cur[h] = v;
            out[((size_t)l * NB + b) * NS + h] = v;      // fire-and-forget
        }
        __syncthreads();
        float* tmp = prev; prev = cur; cur = tmp;
    }
}

// ---------------------------------------------------------------------------
extern "C" void kernel_launch(void* const* d_in, const int* in_sizes, int n_in,
                              void* d_out, int out_size, void* d_ws, size_t ws_size,
                              hipStream_t stream) {
    (void)in_sizes; (void)n_in; (void)out_size; (void)ws_size;
    const int* stories  = (const int*)d_in[0];
    // d_in[1] = story_length (== NL), unused
    const float* priors = (const float*)d_in[2];
    const float* trans  = (const float*)d_in[3];
    const float* em     = (const float*)d_in[4];
    float* out = (float*)d_out;

    float* emT  = (float*)d_ws;                    // [NT][NS]    16 MB
    float* eall = emT + (size_t)NT * NS;           // [NB*NL][NS]  2 MB
    float* wtab = eall + (size_t)NB * NL * NS;     // [7][NS]     57 KB

    const int fwd_lds = ((NL - 1) * NS + 2 * NS) * (int)sizeof(float);  // 139264
    hipFuncSetAttribute((const void*)k_forward,
                        hipFuncAttributeMaxDynamicSharedMemorySize, fwd_lds);

    // grid y: 0..7 = smooth z-slices, 8 = wtab prep
    k_smooth<<<dim3(NT / TT, NZ + 1), 256, 0, stream>>>(em, emT, trans, wtab);
    k_eall<<<dim3(NB * NL, 2), 256, 0, stream>>>(stories, emT, eall);
    k_forward<<<dim3(NB), 1024, fwd_lds, stream>>>(wtab, priors, eall, out);
}